// Round 8
// baseline (208.769 us; speedup 1.0000x reference)
//
#include <hip/hip_runtime.h>
#include <hip/hip_bf16.h>

// VQ-VAE VectorQuantizer — round 13: LDS-amortized screen (64 px/wave) + fused
// resolve.
//   Cross-round finding: dur ~60 µs ≈ SUM of pipe budgets (LDS 22 + MFMA 15 +
//   VALU 18 + misc) — no inter-pipe overlap; occupancy (19-35%) uncorrelated.
//   Fix: halve the biggest pipe. Each wave holds TWO 32-px B-sets (64 px,
//   128 VGPRs) so every A-fragment LDS read feeds 2 MFMAs -> LDS ~11 µs,
//   plus 2 independent acc chains (ILP). 128-thr blocks (2 waves), grid 512,
//   4 blocks/CU. Resolve fused: screen writes widx + loss directly (rare
//   wave-coop exact rescore in-kernel); k_resF eliminated.
//   k_prep2 / k_epi4 unchanged (passing).

#define EMBED_DIM 256
#define N_EMBED   1024
#define HW        4096
#define NPIX      65536
#define BETA      0.25f
#define SBIAS     1024.0f
#define TAU       0.375f

typedef _Float16 h8v __attribute__((ext_vector_type(8)));
typedef __attribute__((ext_vector_type(16))) float f32x16;

// ---------------- workspace layout (float offsets) ----------------
#define NW_ES2T   64              // 34816 h8v = 139264 floats
#define NW_WIDXT  139328          // u16[65536] = 32768 floats
#define NW_EMBTT  172096          // 256*1024 floats
#define NW_ENDT   434240
#define NEEDT_BYTES ((size_t)NW_ENDT * 4)

// fallback (round-1) layout
#define WS_ET_OFF    64
#define WS_NORM_OFF  (64 + EMBED_DIM * N_EMBED)

#define CHUNK2_BYTES (17 * 1024)  // 32-code chunk (17 frags x 1 KB)

__device__ inline void async16(const void* g, void* s) {
    __builtin_amdgcn_global_load_lds(
        (const __attribute__((address_space(1))) unsigned int*)g,
        (__attribute__((address_space(3))) unsigned int*)s, 16, 0, 0);
}

__device__ inline unsigned umin2(unsigned a, unsigned b) { return a < b ? a : b; }
__device__ inline unsigned umax2(unsigned a, unsigned b) { return a < b ? b : a; }

// sorted top-3 insert on packed (score|idx) — pure min/max network (5 ops)
__device__ inline void top3_ins(unsigned u, unsigned& b1, unsigned& b2, unsigned& b3) {
    unsigned t0 = umax2(b1, u);  b1 = umin2(b1, u);
    unsigned t1 = umax2(b2, t0); b2 = umin2(b2, t0);
    b3 = umin2(b3, t1);
}

// ======================= prep kernel =======================
// blocks 0..135   : es2 frag t = (akb*32 + cb)*64 + lane ; akb 16 = norm kb
//                   (||e||^2 + SBIAS as fp16 hi/lo in k=0,1).
// blocks 136..1159: embT[c][j] = emb[j][c] (coalesced reads).

__global__ void k_prep2(const float* __restrict__ emb, _Float16* __restrict__ es2,
                        float* __restrict__ embT, float* __restrict__ out_loss) {
    if (blockIdx.x < 136) {
        int t = blockIdx.x * 256 + threadIdx.x;       // 0..34815
        if (t == 0) *out_loss = 0.f;
        int lane = t & 63;
        int cb   = (t >> 6) & 31;
        int akb  = t >> 11;                           // 0..16
        int m = cb * 32 + (lane & 31);
        int h = lane >> 5;
        _Float16 o[8];
        if (akb < 16) {
            #pragma unroll
            for (int j = 0; j < 8; ++j) {
                int c = akb * 16 + h * 8 + j;
                o[j] = (_Float16)(-2.0f * emb[m * EMBED_DIM + c]);
            }
        } else {
            #pragma unroll
            for (int j = 0; j < 8; ++j) o[j] = (_Float16)0.f;
            if (h == 0) {                             // inline norm
                const float4* row = (const float4*)(emb + (size_t)m * EMBED_DIM);
                float nm = SBIAS;
                #pragma unroll 8
                for (int r = 0; r < 64; ++r) {
                    float4 v = row[r];
                    nm += v.x * v.x + v.y * v.y + v.z * v.z + v.w * v.w;
                }
                _Float16 nh = (_Float16)nm;
                _Float16 nl = (_Float16)(nm - (float)nh);
                o[0] = nh; o[1] = nl;
            }
        }
        *(h8v*)(es2 + (size_t)t * 8) = *(h8v*)o;
    } else {
        int t2 = (blockIdx.x - 136) * 256 + threadIdx.x;   // 0..262143
        int c = t2 & 255;                                  // coalesced read
        int j = t2 >> 8;
        embT[(size_t)c * N_EMBED + j] = emb[(size_t)j * EMBED_DIM + c];
    }
}

// ======================= screen kernel (64 px/wave, fused resolve) ==========
// 128 threads (2 waves), 128 px/block, grid 512 -> 4 blocks/CU.
// Wave covers 64 consecutive px: set0 = [wb,wb+32), set1 = [wb+32,wb+64).
// 32 chunks of 32 codes; each A-frag LDS read feeds mfma(set0)+mfma(set1).

__global__ __launch_bounds__(128, 2)
void k_screen10(const float* __restrict__ z, const float* __restrict__ emb,
                const _Float16* __restrict__ es2,
                unsigned short* __restrict__ widx, float* __restrict__ out_loss) {
    __shared__ __align__(16) char abuf[2 * CHUNK2_BYTES];  // 34 KB
    __shared__ float wsum[2];

    const int tid  = threadIdx.x;
    const int lane = tid & 63;
    const int wv   = tid >> 6;                    // 0..1
    const int pxl  = lane & 31;
    const int h    = lane >> 5;
    const int ln16 = lane * 16;

    // stage chunk 0 (frag f = akb 0..16 at (f*32 + gc)*64 + lane)
    {
        char* bufn = abuf;
        for (int f = wv; f < 17; f += 2) {
            const _Float16* src = es2 + ((size_t)(f * 32) * 64 + lane) * 8;
            async16(src, bufn + f * 1024 + ln16);
        }
    }

    // B fragments for two px-sets; accumulate ||x||^2 per set
    const int wb  = blockIdx.x * 128 + wv * 64;
    const int px0 = wb + pxl;
    const int px1 = wb + 32 + pxl;
    const float* zb0 = z + (size_t)(px0 >> 12) * (EMBED_DIM * HW) + (px0 & 4095);
    const float* zb1 = z + (size_t)(px1 >> 12) * (EMBED_DIM * HW) + (px1 & 4095);

    float nx0 = 0.f, nx1 = 0.f;
    h8v bx0[16], bx1[16];
    #pragma unroll
    for (int kh = 0; kh < 16; ++kh) {
        const int c0 = kh * 16 + h * 8;
        _Float16 o0[8], o1[8];
        #pragma unroll
        for (int j = 0; j < 8; ++j) {
            float v0 = zb0[(size_t)(c0 + j) * HW];
            float v1 = zb1[(size_t)(c0 + j) * HW];
            nx0 += v0 * v0;
            nx1 += v1 * v1;
            o0[j] = (_Float16)v0;
            o1[j] = (_Float16)v1;
        }
        bx0[kh] = *(h8v*)o0;
        bx1[kh] = *(h8v*)o1;
    }
    nx0 += __shfl_xor(nx0, 32, 64);               // full ||x||^2 on both halves
    nx1 += __shfl_xor(nx1, 32, 64);

    h8v bn;                                       // norm-kb B: B[0..1][n] = 1
    #pragma unroll
    for (int j = 0; j < 8; ++j) bn[j] = (_Float16)0.f;
    if (lane < 32) { bn[0] = (_Float16)1.f; bn[1] = (_Float16)1.f; }

    const unsigned maskc = 0xFFFFFC00u;
    unsigned a1_ = 0xFFFFFFFFu, a2_ = 0xFFFFFFFFu, a3_ = 0xFFFFFFFFu;  // set0
    unsigned c1_ = 0xFFFFFFFFu, c2_ = 0xFFFFFFFFu, c3_ = 0xFFFFFFFFu;  // set1

    __syncthreads();                              // chunk-0 staging complete

    for (int c = 0; c < 32; ++c) {
        if (c + 1 < 32) {                         // stage next chunk (overlapped)
            char* bufn = abuf + ((c + 1) & 1) * CHUNK2_BYTES;
            for (int f = wv; f < 17; f += 2) {
                const _Float16* src = es2 + ((size_t)(f * 32 + c + 1) * 64 + lane) * 8;
                async16(src, bufn + f * 1024 + ln16);
            }
        }

        const char* bufc = abuf + (c & 1) * CHUNK2_BYTES;
        f32x16 acc0, acc1;
        #pragma unroll
        for (int r = 0; r < 16; ++r) { acc0[r] = 0.f; acc1[r] = 0.f; }

        // one A-frag read feeds BOTH px-sets (2 independent MFMA chains)
        h8v a = *(const h8v*)(bufc + 0 * 1024 + ln16);
        __builtin_amdgcn_s_setprio(1);
        #pragma unroll
        for (int akb = 0; akb < 16; ++akb) {
            h8v n = *(const h8v*)(bufc + (akb + 1) * 1024 + ln16);
            acc0 = __builtin_amdgcn_mfma_f32_32x32x16_f16(a, bx0[akb], acc0, 0, 0, 0);
            acc1 = __builtin_amdgcn_mfma_f32_32x32x16_f16(a, bx1[akb], acc1, 0, 0, 0);
            a = n;
        }
        acc0 = __builtin_amdgcn_mfma_f32_32x32x16_f16(a, bn, acc0, 0, 0, 0);
        acc1 = __builtin_amdgcn_mfma_f32_32x32x16_f16(a, bn, acc1, 0, 0, 0);
        __builtin_amdgcn_s_setprio(0);

        // packed top-3; C/D: col(px)=lane&31, row=(r&3)+8*(r>>2)+4*(lane>>5)
        const unsigned jb = (unsigned)(c * 32 + h * 4);
        #pragma unroll
        for (int r = 0; r < 16; ++r) {
            const unsigned idx = jb + (unsigned)((r & 3) + 8 * (r >> 2)); // OR-safe
            unsigned u0 = (__float_as_uint(acc0[r]) & maskc) | idx;
            unsigned u1 = (__float_as_uint(acc1[r]) & maskc) | idx;
            top3_ins(u0, a1_, a2_, a3_);
            top3_ins(u1, c1_, c2_, c3_);
        }

        __syncthreads();   // drains staging; guards buffer reuse
    }

    // merge the two k-row halves (lane^32 holds the other 16 rows)
    {
        unsigned o1 = __shfl_xor(a1_, 32, 64);
        unsigned o2 = __shfl_xor(a2_, 32, 64);
        unsigned o3 = __shfl_xor(a3_, 32, 64);
        top3_ins(o1, a1_, a2_, a3_);
        top3_ins(o2, a1_, a2_, a3_);
        top3_ins(o3, a1_, a2_, a3_);
        unsigned p1 = __shfl_xor(c1_, 32, 64);
        unsigned p2 = __shfl_xor(c2_, 32, 64);
        unsigned p3 = __shfl_xor(c3_, 32, 64);
        top3_ins(p1, c1_, c2_, c3_);
        top3_ins(p2, c1_, c2_, c3_);
        top3_ins(p3, c1_, c2_, c3_);
    }

    // lane l owns px wb+l: lanes<32 -> set0 col l, lanes>=32 -> set1 col l-32
    const bool s0 = (lane < 32);
    const unsigned m1 = s0 ? a1_ : c1_;
    const unsigned m2 = s0 ? a2_ : c2_;
    const unsigned m3 = s0 ? a3_ : c3_;
    const float nxf = s0 ? nx0 : nx1;

    const float s1 = __uint_as_float(m1 & maskc);
    const float s2 = __uint_as_float(m2 & maskc);
    int   j  = (int)(m1 & 1023u);
    const int j2 = (int)(m2 & 1023u);
    const int j3 = (int)(m3 & 1023u);
    float d  = s1 - SBIAS + nxf;                  // screen-accurate distance

    // rare exact rescore of flagged (near-tie) pixels — wave-cooperative
    unsigned long long fm = __ballot(s2 - s1 < TAU);
    if (fm) {
        while (fm) {
            const int l = __ffsll(fm) - 1;
            fm &= fm - 1;
            const int fj1 = __shfl(j, l, 64);
            const int fj2 = __shfl(j2, l, 64);
            const int fj3 = __shfl(j3, l, 64);
            const int fpx = wb + l;
            const float* zp = z + (size_t)(fpx >> 12) * (EMBED_DIM * HW) + (fpx & 4095);
            const int cc0 = lane * 4;
            const float4 e1 = *(const float4*)(emb + (size_t)fj1 * EMBED_DIM + cc0);
            const float4 e2 = *(const float4*)(emb + (size_t)fj2 * EMBED_DIM + cc0);
            const float4 e3 = *(const float4*)(emb + (size_t)fj3 * EMBED_DIM + cc0);
            float d1 = 0.f, d2 = 0.f, d3 = 0.f;
            #pragma unroll
            for (int k = 0; k < 4; ++k) {
                const float zv = zp[(size_t)(cc0 + k) * HW];
                float t1 = ((const float*)&e1)[k] - zv; d1 += t1 * t1;
                float t2 = ((const float*)&e2)[k] - zv; d2 += t2 * t2;
                float t3 = ((const float*)&e3)[k] - zv; d3 += t3 * t3;
            }
            #pragma unroll
            for (int off = 32; off; off >>= 1) {
                d1 += __shfl_xor(d1, off, 64);
                d2 += __shfl_xor(d2, off, 64);
                d3 += __shfl_xor(d3, off, 64);
            }
            int bj = fj1; float bd = d1;
            if (d2 < bd || (d2 == bd && fj2 < bj)) { bd = d2; bj = fj2; }
            if (d3 < bd || (d3 == bd && fj3 < bj)) { bd = d3; bj = fj3; }
            if (lane == l) { j = bj; d = bd; }
        }
    }

    widx[wb + lane] = (unsigned short)j;

    float ls = d;
    #pragma unroll
    for (int off = 32; off; off >>= 1) ls += __shfl_xor(ls, off, 64);
    if (lane == 0) wsum[wv] = ls;
    __syncthreads();
    if (tid == 0)
        atomicAdd(out_loss, (wsum[0] + wsum[1]) *
                            (BETA / (float)NPIX / (float)EMBED_DIM));
}

// ======================= streaming epilogue =======================
// One wave per out row (b,c). embT row staged into LDS; random gathers hit
// LDS banks instead of serializing in L1. Contiguous 16 KB stores.

__global__ __launch_bounds__(256)
void k_epi4(const float* __restrict__ embT, const unsigned short* __restrict__ widx,
            float* __restrict__ out) {
    __shared__ float etl[4][N_EMBED];             // 16 KB
    const int tid  = threadIdx.x;
    const int lane = tid & 63;
    const int wv   = tid >> 6;
    const int rowid = blockIdx.x * 4 + wv;        // 0..4095
    const int b = rowid >> 8;
    const int c = rowid & 255;

    const unsigned short* wb = widx + b * HW;
    const float4* et4 = (const float4*)(embT + (size_t)c * N_EMBED);
    float* ob = out + (size_t)b * (EMBED_DIM * HW) + (size_t)c * HW;

    #pragma unroll
    for (int i = 0; i < 4; ++i)                   // wave-private row stage
        *(float4*)&etl[wv][(lane + i * 64) * 4] = et4[lane + i * 64];

    #pragma unroll 4
    for (int t = 0; t < 16; ++t) {
        const int hw = t * 256 + lane * 4;
        const ushort4 jj = *(const ushort4*)(wb + hw);
        float4 v;
        v.x = etl[wv][jj.x];
        v.y = etl[wv][jj.y];
        v.z = etl[wv][jj.z];
        v.w = etl[wv][jj.w];
        *(float4*)(ob + hw) = v;
    }
}

// ======================= fallback (round-1 fp32 path) =======================

__global__ void k_norms(const float* __restrict__ emb, float* __restrict__ norms,
                        float* __restrict__ loss_acc) {
    int j = blockIdx.x;
    int lane = threadIdx.x;
    const float* row = emb + j * EMBED_DIM;
    float s = 0.f;
    #pragma unroll
    for (int r = 0; r < 4; ++r) { float v = row[lane + r * 64]; s += v * v; }
    #pragma unroll
    for (int off = 32; off; off >>= 1) s += __shfl_down(s, off, 64);
    if (lane == 0) norms[j] = s;
    if (blockIdx.x == 0 && lane == 0) loss_acc[0] = 0.f;
}

__global__ void k_final(const float* __restrict__ loss_acc, float* __restrict__ out_loss) {
    *out_loss = (BETA / (float)NPIX / (float)EMBED_DIM) * (*loss_acc);
}

__global__ void k_transpose(const float* __restrict__ emb, float* __restrict__ et) {
    int idx = blockIdx.x * blockDim.x + threadIdx.x;
    int c = idx >> 10;
    int j = idx & 1023;
    et[idx] = -2.0f * emb[j * EMBED_DIM + c];
}

__global__ __launch_bounds__(256, 2)
void k_vq(const float* __restrict__ z, const float* __restrict__ emb,
          const float* __restrict__ et, const float* __restrict__ norms,
          float* __restrict__ out, float* __restrict__ loss_acc)
{
    __shared__ float zt[EMBED_DIM * 64];
    __shared__ float redv[16 * 64];
    __shared__ int   redi[16 * 64];
    __shared__ int   widx[64];
    __shared__ float wsum[4];
    const int tid = threadIdx.x;
    const int wg  = blockIdx.x;
    const int p0  = wg * 64;
    const int b   = p0 >> 12;
    const int hw0 = p0 & 4095;
    const float* zbase = z + (size_t)b * (EMBED_DIM * HW) + hw0;
    {
        const int lane16 = tid & 15;
        const int crow   = tid >> 4;
        #pragma unroll
        for (int r = 0; r < 16; ++r) {
            int c = r * 16 + crow;
            float4 vv = *(const float4*)(zbase + (size_t)c * HW + lane16 * 4);
            *(float4*)&zt[c * 64 + lane16 * 4] = vv;
        }
    }
    __syncthreads();
    const int pxg = tid & 15;
    const int cg  = tid >> 4;
    float bestv[4] = {3.4e38f, 3.4e38f, 3.4e38f, 3.4e38f};
    int   besti[4] = {0, 0, 0, 0};
    for (int chunk = 0; chunk < 16; ++chunk) {
        const int jbase = chunk * 64 + cg * 4;
        float acc[4][4];
        #pragma unroll
        for (int i = 0; i < 4; ++i)
            #pragma unroll
            for (int k = 0; k < 4; ++k) acc[i][k] = 0.f;
        const float* ec = et + jbase;
        #pragma unroll 4
        for (int c = 0; c < EMBED_DIM; ++c) {
            float4 za = *(const float4*)&zt[c * 64 + pxg * 4];
            float4 eb = *(const float4*)(ec + (size_t)c * N_EMBED);
            float zi[4] = {za.x, za.y, za.z, za.w};
            float ek[4] = {eb.x, eb.y, eb.z, eb.w};
            #pragma unroll
            for (int i = 0; i < 4; ++i)
                #pragma unroll
                for (int k = 0; k < 4; ++k)
                    acc[i][k] += zi[i] * ek[k];
        }
        float nn[4];
        #pragma unroll
        for (int k = 0; k < 4; ++k) nn[k] = norms[jbase + k];
        #pragma unroll
        for (int i = 0; i < 4; ++i)
            #pragma unroll
            for (int k = 0; k < 4; ++k) {
                float s = nn[k] + acc[i][k];
                if (s < bestv[i]) { bestv[i] = s; besti[i] = jbase + k; }
            }
    }
    #pragma unroll
    for (int i = 0; i < 4; ++i) {
        redv[cg * 64 + pxg * 4 + i] = bestv[i];
        redi[cg * 64 + pxg * 4 + i] = besti[i];
    }
    __syncthreads();
    if (tid < 64) {
        const int px2 = tid;
        float bv = redv[px2];
        int   bi = redi[px2];
        #pragma unroll
        for (int g = 1; g < 16; ++g) {
            float vv = redv[g * 64 + px2];
            int   ix = redi[g * 64 + px2];
            if (vv < bv || (vv == bv && ix < bi)) { bv = vv; bi = ix; }
        }
        widx[px2] = bi;
    }
    __syncthreads();
    const int px = tid & 63;
    const int wv = tid >> 6;
    const int j  = widx[px];
    const float* qrow = emb + (size_t)j * EMBED_DIM;
    float* obase = out + (size_t)b * (EMBED_DIM * HW) + hw0;
    float lsum = 0.f;
    #pragma unroll 4
    for (int cc = 0; cc < 16; ++cc) {
        const int c0 = wv * 64 + cc * 4;
        float4 q = *(const float4*)(qrow + c0);
        float qv[4] = {q.x, q.y, q.z, q.w};
        #pragma unroll
        for (int k = 0; k < 4; ++k) {
            const int c = c0 + k;
            float zv = zt[c * 64 + px];
            float d = qv[k] - zv;
            lsum += d * d;
            obase[(size_t)c * HW + px] = qv[k];
        }
    }
    #pragma unroll
    for (int off = 32; off; off >>= 1) lsum += __shfl_down(lsum, off, 64);
    if ((tid & 63) == 0) wsum[wv] = lsum;
    __syncthreads();
    if (tid == 0) atomicAdd(loss_acc, wsum[0] + wsum[1] + wsum[2] + wsum[3]);
}

// ======================= launch =======================

extern "C" void kernel_launch(void* const* d_in, const int* in_sizes, int n_in,
                              void* d_out, int out_size, void* d_ws, size_t ws_size,
                              hipStream_t stream) {
    const float* z   = (const float*)d_in[0];
    const float* emb = (const float*)d_in[1];
    float* out       = (float*)d_out;
    float* ws        = (float*)d_ws;

    if (ws_size >= NEEDT_BYTES) {
        _Float16*       es2      = (_Float16*)(ws + NW_ES2T);
        unsigned short* widx     = (unsigned short*)(ws + NW_WIDXT);
        float*          embT     = ws + NW_EMBTT;
        float*          out_loss = out + (size_t)NPIX * EMBED_DIM;

        k_prep2<<<1160, 256, 0, stream>>>(emb, es2, embT, out_loss);
        k_screen10<<<512, 128, 0, stream>>>(z, emb, es2, widx, out_loss);
        k_epi4<<<1024, 256, 0, stream>>>(embT, widx, out);
    } else {
        float* loss_acc = ws;
        float* et       = ws + WS_ET_OFF;
        float* norms    = ws + WS_NORM_OFF;
        k_transpose<<<(EMBED_DIM * N_EMBED) / 256, 256, 0, stream>>>(emb, et);
        k_norms<<<N_EMBED, 64, 0, stream>>>(emb, norms, loss_acc);
        k_vq<<<NPIX / 64, 256, 0, stream>>>(z, emb, et, norms, out, loss_acc);
        k_final<<<1, 1, 0, stream>>>(loss_acc, out + (size_t)NPIX * EMBED_DIM);
    }
}

// Round 10
// 177.287 us; speedup vs baseline: 1.1776x; 1.1776x over previous
//
#include <hip/hip_runtime.h>
#include <hip/hip_bf16.h>

// VQ-VAE VectorQuantizer — round 15: resubmit of round-14 (infra failure).
//   k_screen11: quarter-staged barrier-light screen. 512 thr (8 waves),
//   256 px/block, grid 256 (1 block/CU). LDS holds a QUARTER of the codebook
//   (8 chunks x 17 frags = 136 KB), staged 4x in-place; 8 chunks swept
//   barrier-free between stages (8 barriers total vs 32). Resolve fused.
//   k_prep2 / k_epi4 unchanged (passing).

#define EMBED_DIM 256
#define N_EMBED   1024
#define HW        4096
#define NPIX      65536
#define BETA      0.25f
#define SBIAS     1024.0f
#define TAU       0.375f

typedef _Float16 h8v __attribute__((ext_vector_type(8)));
typedef __attribute__((ext_vector_type(16))) float f32x16;

// ---------------- workspace layout (float offsets) ----------------
#define NW_ES2T   64              // 34816 h8v = 139264 floats
#define NW_WIDXT  139328          // u16[65536] = 32768 floats
#define NW_EMBTT  172096          // 256*1024 floats
#define NW_ENDT   434240
#define NEEDT_BYTES ((size_t)NW_ENDT * 4)

// fallback (round-1) layout
#define WS_ET_OFF    64
#define WS_NORM_OFF  (64 + EMBED_DIM * N_EMBED)

#define QUART_BYTES (136 * 1024)  // 8 chunks x 17 frags x 1 KB

__device__ inline void async16(const void* g, void* s) {
    __builtin_amdgcn_global_load_lds(
        (const __attribute__((address_space(1))) unsigned int*)g,
        (__attribute__((address_space(3))) unsigned int*)s, 16, 0, 0);
}

__device__ inline unsigned umin2(unsigned a, unsigned b) { return a < b ? a : b; }
__device__ inline unsigned umax2(unsigned a, unsigned b) { return a < b ? b : a; }

// sorted top-3 insert on packed (score|idx) — pure min/max network (5 ops)
__device__ inline void top3_ins(unsigned u, unsigned& b1, unsigned& b2, unsigned& b3) {
    unsigned t0 = umax2(b1, u);  b1 = umin2(b1, u);
    unsigned t1 = umax2(b2, t0); b2 = umin2(b2, t0);
    b3 = umin2(b3, t1);
}

// ======================= prep kernel =======================
// blocks 0..135   : es2 frag t = (akb*32 + cb)*64 + lane ; akb 16 = norm kb
//                   (||e||^2 + SBIAS as fp16 hi/lo in k=0,1).
// blocks 136..1159: embT[c][j] = emb[j][c] (coalesced reads).

__global__ void k_prep2(const float* __restrict__ emb, _Float16* __restrict__ es2,
                        float* __restrict__ embT, float* __restrict__ out_loss) {
    if (blockIdx.x < 136) {
        int t = blockIdx.x * 256 + threadIdx.x;       // 0..34815
        if (t == 0) *out_loss = 0.f;
        int lane = t & 63;
        int cb   = (t >> 6) & 31;
        int akb  = t >> 11;                           // 0..16
        int m = cb * 32 + (lane & 31);
        int h = lane >> 5;
        _Float16 o[8];
        if (akb < 16) {
            #pragma unroll
            for (int j = 0; j < 8; ++j) {
                int c = akb * 16 + h * 8 + j;
                o[j] = (_Float16)(-2.0f * emb[m * EMBED_DIM + c]);
            }
        } else {
            #pragma unroll
            for (int j = 0; j < 8; ++j) o[j] = (_Float16)0.f;
            if (h == 0) {                             // inline norm
                const float4* row = (const float4*)(emb + (size_t)m * EMBED_DIM);
                float nm = SBIAS;
                #pragma unroll 8
                for (int r = 0; r < 64; ++r) {
                    float4 v = row[r];
                    nm += v.x * v.x + v.y * v.y + v.z * v.z + v.w * v.w;
                }
                _Float16 nh = (_Float16)nm;
                _Float16 nl = (_Float16)(nm - (float)nh);
                o[0] = nh; o[1] = nl;
            }
        }
        *(h8v*)(es2 + (size_t)t * 8) = *(h8v*)o;
    } else {
        int t2 = (blockIdx.x - 136) * 256 + threadIdx.x;   // 0..262143
        int c = t2 & 255;                                  // coalesced read
        int j = t2 >> 8;
        embT[(size_t)c * N_EMBED + j] = emb[(size_t)j * EMBED_DIM + c];
    }
}

// ======================= screen kernel (quarter-staged) =======================
// 512 threads (8 waves), 256 px/block, grid 256 (1 block/CU). LDS holds a
// QUARTER of the codebook (8 chunks x 17 frags = 136 KB), staged 4x in-place.
// Between stages: 8 chunks swept with NO barriers. Resolve fused.

__global__ __launch_bounds__(512, 2)
void k_screen11(const float* __restrict__ z, const float* __restrict__ emb,
                const _Float16* __restrict__ es2,
                unsigned short* __restrict__ widx, float* __restrict__ out_loss) {
    __shared__ __align__(16) char abuf[QUART_BYTES];   // 136 KB (1 block/CU)
    __shared__ float wsum[8];

    const int tid  = threadIdx.x;
    const int lane = tid & 63;
    const int wv   = tid >> 6;                    // 0..7
    const int pxl  = lane & 31;
    const int h    = lane >> 5;
    const int ln16 = lane * 16;

    // stage quarter 0: 136 frags, 17 per wave. frag (ch,f) <- es2 code-chunk
    // (q*8+ch), akb f ; LDS offset (ch*17+f)*1024.
    {
        for (int i = 0; i < 17; ++i) {
            const int fg = wv + i * 8;                 // 0..135
            if (fg < 136) {
                const int ch = fg / 17, f = fg % 17;
                const _Float16* src = es2 + ((size_t)(f * 32 + ch) * 64 + lane) * 8;
                async16(src, abuf + (ch * 17 + f) * 1024 + ln16);
            }
        }
    }

    // build B fragments (hi-only fp16) straight from z; accumulate ||x||^2
    const int wb = blockIdx.x * 256 + wv * 32;    // wave's first px
    const int px = wb + pxl;
    const float* zb = z + (size_t)(px >> 12) * (EMBED_DIM * HW) + (px & 4095);

    float nx = 0.f;
    h8v bx[16];
    #pragma unroll
    for (int kh = 0; kh < 16; ++kh) {
        const int c0 = kh * 16 + h * 8;
        _Float16 oh[8];
        #pragma unroll
        for (int j = 0; j < 8; ++j) {
            float v = zb[(size_t)(c0 + j) * HW];
            nx += v * v;
            oh[j] = (_Float16)v;
        }
        bx[kh] = *(h8v*)oh;
    }
    nx += __shfl_xor(nx, 32, 64);                 // full ||x||^2 on both halves

    h8v bn;                                       // norm-kb B: B[0..1][n] = 1
    #pragma unroll
    for (int j = 0; j < 8; ++j) bn[j] = (_Float16)0.f;
    if (lane < 32) { bn[0] = (_Float16)1.f; bn[1] = (_Float16)1.f; }

    const unsigned maskc = 0xFFFFFC00u;
    unsigned b1 = 0xFFFFFFFFu, b2 = 0xFFFFFFFFu, b3 = 0xFFFFFFFFu;

    __syncthreads();                              // quarter-0 staging complete

    for (int q = 0; q < 4; ++q) {
        // ---- 8 chunks, barrier-free ----
        for (int ch = 0; ch < 8; ++ch) {
            const char* bufc = abuf + ch * 17 * 1024;
            f32x16 acc;
            #pragma unroll
            for (int r = 0; r < 16; ++r) acc[r] = 0.f;

            h8v a = *(const h8v*)(bufc + 0 * 1024 + ln16);
            __builtin_amdgcn_s_setprio(1);
            #pragma unroll
            for (int akb = 0; akb < 16; ++akb) {
                h8v n = *(const h8v*)(bufc + (akb + 1) * 1024 + ln16);
                acc = __builtin_amdgcn_mfma_f32_32x32x16_f16(a, bx[akb], acc, 0, 0, 0);
                a = n;
            }
            acc = __builtin_amdgcn_mfma_f32_32x32x16_f16(a, bn, acc, 0, 0, 0);
            __builtin_amdgcn_s_setprio(0);

            // packed top-3; C/D: col(px)=lane&31, row=(r&3)+8*(r>>2)+4*h
            const unsigned jb = (unsigned)((q * 8 + ch) * 32 + h * 4);
            #pragma unroll
            for (int r = 0; r < 16; ++r) {
                const unsigned idx = jb + (unsigned)((r & 3) + 8 * (r >> 2));
                unsigned u = (__float_as_uint(acc[r]) & maskc) | idx;
                top3_ins(u, b1, b2, b3);
            }
        }

        // ---- restage in place for next quarter ----
        if (q < 3) {
            __syncthreads();                      // all waves done reading
            for (int i = 0; i < 17; ++i) {
                const int fg = wv + i * 8;
                if (fg < 136) {
                    const int ch = fg / 17, f = fg % 17;
                    const _Float16* src = es2 +
                        ((size_t)(f * 32 + (q + 1) * 8 + ch) * 64 + lane) * 8;
                    async16(src, abuf + (ch * 17 + f) * 1024 + ln16);
                }
            }
            __syncthreads();                      // staging complete
        }
    }

    // merge the two k-row halves (lane^32 holds the other 16 rows)
    {
        unsigned o1 = __shfl_xor(b1, 32, 64);
        unsigned o2 = __shfl_xor(b2, 32, 64);
        unsigned o3 = __shfl_xor(b3, 32, 64);
        top3_ins(o1, b1, b2, b3);
        top3_ins(o2, b1, b2, b3);
        top3_ins(o3, b1, b2, b3);
    }

    // fused resolve: lane l (<32) owns px wb+l
    const float s1 = __uint_as_float(b1 & maskc);
    const float s2 = __uint_as_float(b2 & maskc);
    int   j  = (int)(b1 & 1023u);
    const int j2 = (int)(b2 & 1023u);
    const int j3 = (int)(b3 & 1023u);
    float d  = s1 - SBIAS + nx;                   // screen-accurate distance

    unsigned long long fm = __ballot(lane < 32 && (s2 - s1 < TAU));
    if (fm) {
        while (fm) {
            const int l = __ffsll(fm) - 1;        // l < 32
            fm &= fm - 1;
            const int fj1 = __shfl(j, l, 64);
            const int fj2 = __shfl(j2, l, 64);
            const int fj3 = __shfl(j3, l, 64);
            const int fpx = wb + l;
            const float* zp = z + (size_t)(fpx >> 12) * (EMBED_DIM * HW) + (fpx & 4095);
            const int cc0 = lane * 4;
            const float4 e1 = *(const float4*)(emb + (size_t)fj1 * EMBED_DIM + cc0);
            const float4 e2 = *(const float4*)(emb + (size_t)fj2 * EMBED_DIM + cc0);
            const float4 e3 = *(const float4*)(emb + (size_t)fj3 * EMBED_DIM + cc0);
            float d1 = 0.f, d2 = 0.f, d3 = 0.f;
            #pragma unroll
            for (int k = 0; k < 4; ++k) {
                const float zv = zp[(size_t)(cc0 + k) * HW];
                float t1 = ((const float*)&e1)[k] - zv; d1 += t1 * t1;
                float t2 = ((const float*)&e2)[k] - zv; d2 += t2 * t2;
                float t3 = ((const float*)&e3)[k] - zv; d3 += t3 * t3;
            }
            #pragma unroll
            for (int off = 32; off; off >>= 1) {
                d1 += __shfl_xor(d1, off, 64);
                d2 += __shfl_xor(d2, off, 64);
                d3 += __shfl_xor(d3, off, 64);
            }
            int bj = fj1; float bd = d1;
            if (d2 < bd || (d2 == bd && fj2 < bj)) { bd = d2; bj = fj2; }
            if (d3 < bd || (d3 == bd && fj3 < bj)) { bd = d3; bj = fj3; }
            if (lane == l) { j = bj; d = bd; }
        }
    }

    if (lane < 32) widx[wb + lane] = (unsigned short)j;

    float ls = (lane < 32) ? d : 0.f;
    #pragma unroll
    for (int off = 32; off; off >>= 1) ls += __shfl_xor(ls, off, 64);
    if (lane == 0) wsum[wv] = ls;
    __syncthreads();
    if (tid == 0) {
        float t = 0.f;
        #pragma unroll
        for (int w = 0; w < 8; ++w) t += wsum[w];
        atomicAdd(out_loss, t * (BETA / (float)NPIX / (float)EMBED_DIM));
    }
}

// ======================= streaming epilogue =======================
// One wave per out row (b,c). embT row staged into LDS; random gathers hit
// LDS banks instead of serializing in L1. Contiguous 16 KB stores.

__global__ __launch_bounds__(256)
void k_epi4(const float* __restrict__ embT, const unsigned short* __restrict__ widx,
            float* __restrict__ out) {
    __shared__ float etl[4][N_EMBED];             // 16 KB
    const int tid  = threadIdx.x;
    const int lane = tid & 63;
    const int wv   = tid >> 6;
    const int rowid = blockIdx.x * 4 + wv;        // 0..4095
    const int b = rowid >> 8;
    const int c = rowid & 255;

    const unsigned short* wb = widx + b * HW;
    const float4* et4 = (const float4*)(embT + (size_t)c * N_EMBED);
    float* ob = out + (size_t)b * (EMBED_DIM * HW) + (size_t)c * HW;

    #pragma unroll
    for (int i = 0; i < 4; ++i)                   // wave-private row stage
        *(float4*)&etl[wv][(lane + i * 64) * 4] = et4[lane + i * 64];

    #pragma unroll 4
    for (int t = 0; t < 16; ++t) {
        const int hw = t * 256 + lane * 4;
        const ushort4 jj = *(const ushort4*)(wb + hw);
        float4 v;
        v.x = etl[wv][jj.x];
        v.y = etl[wv][jj.y];
        v.z = etl[wv][jj.z];
        v.w = etl[wv][jj.w];
        *(float4*)(ob + hw) = v;
    }
}

// ======================= fallback (round-1 fp32 path) =======================

__global__ void k_norms(const float* __restrict__ emb, float* __restrict__ norms,
                        float* __restrict__ loss_acc) {
    int j = blockIdx.x;
    int lane = threadIdx.x;
    const float* row = emb + j * EMBED_DIM;
    float s = 0.f;
    #pragma unroll
    for (int r = 0; r < 4; ++r) { float v = row[lane + r * 64]; s += v * v; }
    #pragma unroll
    for (int off = 32; off; off >>= 1) s += __shfl_down(s, off, 64);
    if (lane == 0) norms[j] = s;
    if (blockIdx.x == 0 && lane == 0) loss_acc[0] = 0.f;
}

__global__ void k_final(const float* __restrict__ loss_acc, float* __restrict__ out_loss) {
    *out_loss = (BETA / (float)NPIX / (float)EMBED_DIM) * (*loss_acc);
}

__global__ void k_transpose(const float* __restrict__ emb, float* __restrict__ et) {
    int idx = blockIdx.x * blockDim.x + threadIdx.x;
    int c = idx >> 10;
    int j = idx & 1023;
    et[idx] = -2.0f * emb[j * EMBED_DIM + c];
}

__global__ __launch_bounds__(256, 2)
void k_vq(const float* __restrict__ z, const float* __restrict__ emb,
          const float* __restrict__ et, const float* __restrict__ norms,
          float* __restrict__ out, float* __restrict__ loss_acc)
{
    __shared__ float zt[EMBED_DIM * 64];
    __shared__ float redv[16 * 64];
    __shared__ int   redi[16 * 64];
    __shared__ int   widx[64];
    __shared__ float wsum[4];
    const int tid = threadIdx.x;
    const int wg  = blockIdx.x;
    const int p0  = wg * 64;
    const int b   = p0 >> 12;
    const int hw0 = p0 & 4095;
    const float* zbase = z + (size_t)b * (EMBED_DIM * HW) + hw0;
    {
        const int lane16 = tid & 15;
        const int crow   = tid >> 4;
        #pragma unroll
        for (int r = 0; r < 16; ++r) {
            int c = r * 16 + crow;
            float4 vv = *(const float4*)(zbase + (size_t)c * HW + lane16 * 4);
            *(float4*)&zt[c * 64 + lane16 * 4] = vv;
        }
    }
    __syncthreads();
    const int pxg = tid & 15;
    const int cg  = tid >> 4;
    float bestv[4] = {3.4e38f, 3.4e38f, 3.4e38f, 3.4e38f};
    int   besti[4] = {0, 0, 0, 0};
    for (int chunk = 0; chunk < 16; ++chunk) {
        const int jbase = chunk * 64 + cg * 4;
        float acc[4][4];
        #pragma unroll
        for (int i = 0; i < 4; ++i)
            #pragma unroll
            for (int k = 0; k < 4; ++k) acc[i][k] = 0.f;
        const float* ec = et + jbase;
        #pragma unroll 4
        for (int c = 0; c < EMBED_DIM; ++c) {
            float4 za = *(const float4*)&zt[c * 64 + pxg * 4];
            float4 eb = *(const float4*)(ec + (size_t)c * N_EMBED);
            float zi[4] = {za.x, za.y, za.z, za.w};
            float ek[4] = {eb.x, eb.y, eb.z, eb.w};
            #pragma unroll
            for (int i = 0; i < 4; ++i)
                #pragma unroll
                for (int k = 0; k < 4; ++k)
                    acc[i][k] += zi[i] * ek[k];
        }
        float nn[4];
        #pragma unroll
        for (int k = 0; k < 4; ++k) nn[k] = norms[jbase + k];
        #pragma unroll
        for (int i = 0; i < 4; ++i)
            #pragma unroll
            for (int k = 0; k < 4; ++k) {
                float s = nn[k] + acc[i][k];
                if (s < bestv[i]) { bestv[i] = s; besti[i] = jbase + k; }
            }
    }
    #pragma unroll
    for (int i = 0; i < 4; ++i) {
        redv[cg * 64 + pxg * 4 + i] = bestv[i];
        redi[cg * 64 + pxg * 4 + i] = besti[i];
    }
    __syncthreads();
    if (tid < 64) {
        const int px2 = tid;
        float bv = redv[px2];
        int   bi = redi[px2];
        #pragma unroll
        for (int g = 1; g < 16; ++g) {
            float vv = redv[g * 64 + px2];
            int   ix = redi[g * 64 + px2];
            if (vv < bv || (vv == bv && ix < bi)) { bv = vv; bi = ix; }
        }
        widx[px2] = bi;
    }
    __syncthreads();
    const int px = tid & 63;
    const int wv = tid >> 6;
    const int j  = widx[px];
    const float* qrow = emb + (size_t)j * EMBED_DIM;
    float* obase = out + (size_t)b * (EMBED_DIM * HW) + hw0;
    float lsum = 0.f;
    #pragma unroll 4
    for (int cc = 0; cc < 16; ++cc) {
        const int c0 = wv * 64 + cc * 4;
        float4 q = *(const float4*)(qrow + c0);
        float qv[4] = {q.x, q.y, q.z, q.w};
        #pragma unroll
        for (int k = 0; k < 4; ++k) {
            const int c = c0 + k;
            float zv = zt[c * 64 + px];
            float d = qv[k] - zv;
            lsum += d * d;
            obase[(size_t)c * HW + px] = qv[k];
        }
    }
    #pragma unroll
    for (int off = 32; off; off >>= 1) lsum += __shfl_down(lsum, off, 64);
    if ((tid & 63) == 0) wsum[wv] = lsum;
    __syncthreads();
    if (tid == 0) atomicAdd(loss_acc, wsum[0] + wsum[1] + wsum[2] + wsum[3]);
}

// ======================= launch =======================

extern "C" void kernel_launch(void* const* d_in, const int* in_sizes, int n_in,
                              void* d_out, int out_size, void* d_ws, size_t ws_size,
                              hipStream_t stream) {
    const float* z   = (const float*)d_in[0];
    const float* emb = (const float*)d_in[1];
    float* out       = (float*)d_out;
    float* ws        = (float*)d_ws;

    if (ws_size >= NEEDT_BYTES) {
        _Float16*       es2      = (_Float16*)(ws + NW_ES2T);
        unsigned short* widx     = (unsigned short*)(ws + NW_WIDXT);
        float*          embT     = ws + NW_EMBTT;
        float*          out_loss = out + (size_t)NPIX * EMBED_DIM;

        k_prep2<<<1160, 256, 0, stream>>>(emb, es2, embT, out_loss);
        k_screen11<<<256, 512, 0, stream>>>(z, emb, es2, widx, out_loss);
        k_epi4<<<1024, 256, 0, stream>>>(embT, widx, out);
    } else {
        float* loss_acc = ws;
        float* et       = ws + WS_ET_OFF;
        float* norms    = ws + WS_NORM_OFF;
        k_transpose<<<(EMBED_DIM * N_EMBED) / 256, 256, 0, stream>>>(emb, et);
        k_norms<<<N_EMBED, 64, 0, stream>>>(emb, norms, loss_acc);
        k_vq<<<NPIX / 64, 256, 0, stream>>>(z, emb, et, norms, out, loss_acc);
        k_final<<<1, 1, 0, stream>>>(loss_acc, out + (size_t)NPIX * EMBED_DIM);
    }
}